// Round 11
// baseline (81.059 us; speedup 1.0000x reference)
//
#include <hip/hip_runtime.h>
#include <hip/hip_fp16.h>

#define N_NODES 50000
#define N_EDGES 250000
#define N_GRAPHS 512
#define F_IN 32
#define F_EDGE 16
#define LATENT 32
#define EMBED 128
#define E_BLK 256
#define N_EBLK ((N_EDGES + E_BLK - 1) / E_BLK)  // 977
#define KW 1056                                  // W2T row length: 1024 + 32 (b2 fold)
#define HS_STRIDE 36                             // Hs2 row stride in dwords (16B aligned)

typedef unsigned short ushort;
typedef unsigned int uint;
typedef _Float16 half8v __attribute__((ext_vector_type(8)));
typedef _Float16 half2v __attribute__((ext_vector_type(2)));
typedef __attribute__((ext_vector_type(4))) float f32x4;

union UH8 { half8v h8; half2v h2[4]; ushort u[8]; uint q[4]; };
union UH2 { half2v h2; uint q; };

__device__ inline ushort f2h_bits(float f) {
    _Float16 h = (_Float16)f;
    return *reinterpret_cast<ushort*>(&h);
}

// ---------------- prep: zero agg(f16)/pool + x->f16 + W2T(f16) [32 l][1056 kk] ----------------
// kk < 1024:  W2T[l][kk] = W2.flat[kk*32 + l]
// kk >= 1024: W2T[l][1024+f] = b2[f*32 + l]    (b2 folded; paired with h == 1)
__global__ void prep_kernel(const float* __restrict__ x, const float* __restrict__ W2,
                            const float* __restrict__ b2, ushort* __restrict__ xh,
                            ushort* __restrict__ W2T, uint4* __restrict__ aggz,
                            float* __restrict__ pool, float* __restrict__ pcnt) {
    int i = blockIdx.x * blockDim.x + threadIdx.x;
    if (i < (N_NODES * F_IN) / 4) {
        float4 v = ((const float4*)x)[i];
        union { ushort u[4]; uint2 q; } pk;
        pk.u[0] = f2h_bits(v.x); pk.u[1] = f2h_bits(v.y);
        pk.u[2] = f2h_bits(v.z); pk.u[3] = f2h_bits(v.w);
        ((uint2*)xh)[i] = pk.q;
    }
    if (i < (N_NODES * LATENT * 2) / 16) aggz[i] = make_uint4(0u, 0u, 0u, 0u);  // agg f16 zeros
    if (i < 32 * 1024) {
        int kk = i >> 5, l = i & 31;
        W2T[l * KW + kk] = f2h_bits(W2[i]);   // coalesced read
    }
    if (i < 1024) {
        int f = i >> 5, l = i & 31;
        W2T[l * KW + 1024 + f] = f2h_bits(b2[i]);
    }
    if (i < N_GRAPHS * LATENT) pool[i] = 0.f;
    if (i < N_GRAPHS) pcnt[i] = 0.f;
}

// ---------------- edge kernel: MSG[E x 32] = G[E x 1056] @ W2T^T  (f16 MFMA) ----------------
// G[e, k*32+f] = h[e,k] * x[src_e, f]  (k<32) ;  G[e, 1024+f] = x[src_e, f]
// MFMA 16x16x32: A row i = lane&15, k-slot = (lane>>4)*8+b;
//                D col j = lane&15, row i = (lane>>4)*4 + reg.
// 512 threads = 8 waves; each wave owns 2 16-row M-tiles (256 edges/block).
// B-fragments read DIRECTLY from W2T (66KB, L1/L2-resident) with immediate offsets —
// no W2q staging, no K-loop barriers (single barrier after H-phase).
// Scatter: packed f16 atomics (global_atomic_pk_add_f16), 2 cols per lane-atomic.
__global__ __launch_bounds__(512, 6) void edge_mfma_kernel(
    const ushort* __restrict__ xh, const int* __restrict__ ei,
    const float* __restrict__ ea, const float* __restrict__ W1,
    const float* __restrict__ b1, const ushort* __restrict__ W2T,
    __half* __restrict__ aggh)
{
    __shared__ __attribute__((aligned(16))) uint Hs2[E_BLK * HS_STRIDE]; // {h,h} f16, 36KB

    const int t = threadIdx.x;
    const int e0 = blockIdx.x * E_BLK;
    const int wv = t >> 6, lane = t & 63;
    const int g = lane >> 4, j16 = lane & 15;

    // per-lane B-row base pointers (immediate offsets q*512+kst*64 cover the rest)
    const ushort* w2r0 = W2T + (size_t)j16 * KW + 8 * g;
    const ushort* w2r1 = W2T + (size_t)(16 + j16) * KW + 8 * g;

    // ---- H = relu(ea @ W1 + b1) via K-padded f16 MFMA (f>=16 lanes hold zeros)
    UH8 bw[2];
    #pragma unroll
    for (int nt = 0; nt < 2; ++nt) {
        #pragma unroll
        for (int b = 0; b < 8; ++b) {
            float w = (g < 2) ? W1[(8 * g + b) * LATENT + nt * 16 + j16] : 0.f;
            bw[nt].u[b] = f2h_bits(w);
        }
    }
    float b1v[2] = { b1[j16], b1[16 + j16] };

    #pragma unroll
    for (int mt = 0; mt < 2; ++mt) {
        int mtg = 2 * wv + mt;               // 0..15
        int rowA = mtg * 16 + j16;
        int e = e0 + rowA; if (e >= N_EDGES) e = N_EDGES - 1;
        UH8 ae;
        if (g < 2) {
            const float4* p = (const float4*)(ea + (size_t)e * F_EDGE + 8 * g);
            float4 va = p[0], vb = p[1];
            ae.u[0] = f2h_bits(va.x); ae.u[1] = f2h_bits(va.y);
            ae.u[2] = f2h_bits(va.z); ae.u[3] = f2h_bits(va.w);
            ae.u[4] = f2h_bits(vb.x); ae.u[5] = f2h_bits(vb.y);
            ae.u[6] = f2h_bits(vb.z); ae.u[7] = f2h_bits(vb.w);
        } else {
            ae.q[0] = 0; ae.q[1] = 0; ae.q[2] = 0; ae.q[3] = 0;
        }
        #pragma unroll
        for (int nt = 0; nt < 2; ++nt) {
            f32x4 hacc = (f32x4){0.f, 0.f, 0.f, 0.f};
            hacc = __builtin_amdgcn_mfma_f32_16x16x32_f16(ae.h8, bw[nt].h8, hacc, 0, 0, 0);
            #pragma unroll
            for (int v = 0; v < 4; ++v) {
                int rowD = mtg * 16 + 4 * g + v;
                int col = nt * 16 + j16;
                float hval = fmaxf(hacc[v] + b1v[nt], 0.f);
                uint hb = (uint)f2h_bits(hval);
                Hs2[rowD * HS_STRIDE + col] = hb * 0x10001u;  // packed {h,h}
            }
        }
    }
    // b2-extension row: h == 1.0 for every edge (k = 32)
    if (t < E_BLK) Hs2[t * HS_STRIDE + 32] = 0x3C003C00u;

    // ---- xh fragments (f16, reused across all K): lane's 8 f-values (f = 8g+b) per M-tile
    f32x4 acc[2][2];
    #pragma unroll
    for (int a = 0; a < 2; ++a)
        #pragma unroll
        for (int b = 0; b < 2; ++b) acc[a][b] = (f32x4){0.f, 0.f, 0.f, 0.f};

    UH8 xf[2];
    int myrow[2];
    #pragma unroll
    for (int mt = 0; mt < 2; ++mt) {
        int row = (2 * wv + mt) * 16 + j16;
        myrow[mt] = row;
        int e = e0 + row; if (e >= N_EDGES) e = N_EDGES - 1;
        int src = ei[e];
        uint4 raw = *(const uint4*)(xh + (size_t)src * F_IN + 8 * g);
        xf[mt].q[0] = raw.x; xf[mt].q[1] = raw.y; xf[mt].q[2] = raw.z; xf[mt].q[3] = raw.w;
    }

    // ---- b2-extension K-step: A = x fragment directly (h == 1); B at kk=1024+8g
    {
        UH8 bx0, bx1;
        *(uint4*)bx0.q = *(const uint4*)(w2r0 + 1024);
        *(uint4*)bx1.q = *(const uint4*)(w2r1 + 1024);
        #pragma unroll
        for (int mt = 0; mt < 2; ++mt) {
            acc[mt][0] = __builtin_amdgcn_mfma_f32_16x16x32_f16(xf[mt].h8, bx0.h8, acc[mt][0], 0, 0, 0);
            acc[mt][1] = __builtin_amdgcn_mfma_f32_16x16x32_f16(xf[mt].h8, bx1.h8, acc[mt][1], 0, 0, 0);
        }
    }

    __syncthreads();  // Hs2 (incl. cross-wave b2 row) visible to all — the ONLY barrier

    // ---- K loop: 4 quarters of 256 kk; B-fragments straight from W2T (cache-resident)
    #pragma unroll
    for (int q = 0; q < 4; ++q) {
        // batched h2 fetch: 8 packed {h,h} per M-tile for k = q*8 .. q*8+7
        uint hb[2][8];
        #pragma unroll
        for (int mt = 0; mt < 2; ++mt) {
            const uint* hp = Hs2 + myrow[mt] * HS_STRIDE + q * 8;
            uint4 a = *(const uint4*)hp;
            uint4 b = *(const uint4*)(hp + 4);
            hb[mt][0] = a.x; hb[mt][1] = a.y; hb[mt][2] = a.z; hb[mt][3] = a.w;
            hb[mt][4] = b.x; hb[mt][5] = b.y; hb[mt][6] = b.z; hb[mt][7] = b.w;
        }

        #pragma unroll
        for (int kst = 0; kst < 8; ++kst) {
            UH8 bf0, bf1;
            *(uint4*)bf0.q = *(const uint4*)(w2r0 + q * 256 + kst * 32);  // imm offset
            *(uint4*)bf1.q = *(const uint4*)(w2r1 + q * 256 + kst * 32);
            #pragma unroll
            for (int mt = 0; mt < 2; ++mt) {
                UH2 h2; h2.q = hb[mt][kst];
                UH8 af;
                #pragma unroll
                for (int p = 0; p < 4; ++p) af.h2[p] = h2.h2 * xf[mt].h2[p];  // v_pk_mul_f16
                acc[mt][0] = __builtin_amdgcn_mfma_f32_16x16x32_f16(af.h8, bf0.h8, acc[mt][0], 0, 0, 0);
                acc[mt][1] = __builtin_amdgcn_mfma_f32_16x16x32_f16(af.h8, bf1.h8, acc[mt][1], 0, 0, 0);
            }
        }
    }

    // ---- scatter-add to aggh[dst] with packed-f16 atomics (2 cols per lane-atomic)
    const int odd = j16 & 1;
    #pragma unroll
    for (int mt = 0; mt < 2; ++mt) {
        int rowb = (2 * wv + mt) * 16 + 4 * g;
        #pragma unroll
        for (int v = 0; v < 4; ++v) {
            int e = e0 + rowb + v;
            float a0 = acc[mt][0][v], a1 = acc[mt][1][v];
            float p0 = __shfl_xor(a0, 1);
            float p1 = __shfl_xor(a1, 1);
            if (e < N_EDGES) {
                int dst = ei[N_EDGES + e];
                __half2 hv = odd ? __floats2half2_rn(p1, a1) : __floats2half2_rn(a0, p0);
                int col = odd ? (15 + j16) : j16;
                unsafeAtomicAdd((__half2*)(aggh + (size_t)dst * LATENT + col), hv);
            }
        }
    }
}

// ---------------- node update + global mean pool ----------------
// Lane l owns column l; each 32-lane group walks VN consecutive nodes with a running
// per-graph partial sum (batch sorted -> ~1 atomic flush per graph-run per stripe).
#define VN 8
__global__ __launch_bounds__(256) void nodepool_kernel(
    const float* __restrict__ x, const __half* __restrict__ aggh,
    const float* __restrict__ root, const float* __restrict__ cbias,
    const int* __restrict__ batch, float* __restrict__ pool,
    float* __restrict__ pcnt)
{
    int t = threadIdx.x;
    int l = t & 31;
    int stripe = t >> 5;  // 0..7
    int v0 = (blockIdx.x * 8 + stripe) * VN;
    float rc[F_IN];
    #pragma unroll
    for (int f = 0; f < F_IN; ++f) rc[f] = root[f * LATENT + l];
    float cbl = cbias[l];

    float sum = 0.f, cnt = 0.f;
    int gcur = -1;
    for (int i = 0; i < VN; ++i) {
        int v = v0 + i;
        if (v >= N_NODES) break;
        int g = batch[v];
        if (g != gcur) {
            if (gcur >= 0) {
                atomicAdd(&pool[gcur * LATENT + l], sum);
                if (l == 0) atomicAdd(&pcnt[gcur], cnt);
            }
            gcur = g; sum = 0.f; cnt = 0.f;
        }
        float xv = x[(size_t)v * F_IN + l];     // coalesced
        float a = __half2float(aggh[(size_t)v * LATENT + l]) + cbl;
        #pragma unroll
        for (int f = 0; f < F_IN; ++f) {
            float xfv = __shfl(xv, (t & 32) | f);
            a += xfv * rc[f];
        }
        sum += fmaxf(a, 0.f);
        cnt += 1.f;
    }
    if (gcur >= 0) {
        atomicAdd(&pool[gcur * LATENT + l], sum);
        if (l == 0) atomicAdd(&pcnt[gcur], cnt);
    }
}

// ---------------- final FC ----------------
__global__ void final_kernel(const float* __restrict__ pool, const float* __restrict__ pcnt,
                             const float* __restrict__ fcw, const float* __restrict__ fcb,
                             float* __restrict__ out)
{
    int t = blockIdx.x * blockDim.x + threadIdx.x;
    int gr = t >> 7, j = t & 127;
    if (gr >= N_GRAPHS) return;
    float inv = 1.0f / fmaxf(pcnt[gr], 1.0f);
    float o = fcb[j];
    #pragma unroll 8
    for (int l = 0; l < LATENT; ++l) {
        float pv = fmaxf(pool[gr * LATENT + l] * inv, 0.0f);
        o += pv * fcw[l * EMBED + j];
    }
    out[gr * EMBED + j] = o;
}

extern "C" void kernel_launch(void* const* d_in, const int* in_sizes, int n_in,
                              void* d_out, int out_size, void* d_ws, size_t ws_size,
                              hipStream_t stream)
{
    const float* x     = (const float*)d_in[0];
    const int*   ei    = (const int*)d_in[1];
    const float* ea    = (const float*)d_in[2];
    const int*   batch = (const int*)d_in[3];
    const float* W1    = (const float*)d_in[4];
    const float* b1    = (const float*)d_in[5];
    const float* W2    = (const float*)d_in[6];
    const float* b2    = (const float*)d_in[7];
    const float* root  = (const float*)d_in[8];
    const float* cb    = (const float*)d_in[9];
    const float* fcw   = (const float*)d_in[10];
    const float* fcb   = (const float*)d_in[11];
    float* out = (float*)d_out;

    char* w = (char*)d_ws;
    auto alloc = [&](size_t bytes) {
        char* p = w;
        w += (bytes + 255) & ~size_t(255);
        return p;
    };
    ushort* W2T  = (ushort*)alloc((size_t)32 * KW * 2);
    ushort* xh   = (ushort*)alloc((size_t)N_NODES * F_IN * 2);
    __half* aggh = (__half*)alloc((size_t)N_NODES * LATENT * 2);
    float*  pool = (float*)alloc(N_GRAPHS * LATENT * 4);
    float*  pcnt = (float*)alloc(N_GRAPHS * 4);

    prep_kernel<<<1563, 256, 0, stream>>>(x, W2, b2, xh, W2T, (uint4*)aggh, pool, pcnt);
    edge_mfma_kernel<<<N_EBLK, 512, 0, stream>>>(xh, ei, ea, W1, b1, W2T, aggh);
    nodepool_kernel<<<(N_NODES + 8 * VN - 1) / (8 * VN), 256, 0, stream>>>(
        x, aggh, root, cb, batch, pool, pcnt);
    final_kernel<<<(N_GRAPHS * EMBED + 255) / 256, 256, 0, stream>>>(pool, pcnt, fcw, fcb, out);
}

// Round 13
// 63.012 us; speedup vs baseline: 1.2864x; 1.2864x over previous
//
#include <hip/hip_runtime.h>
#include <hip/hip_fp16.h>

#define N_NODES 50000
#define N_EDGES 250000
#define N_GRAPHS 512
#define F_IN 32
#define F_EDGE 16
#define LATENT 32
#define EMBED 128
#define E_BLK 256
#define N_EBLK ((N_EDGES + E_BLK - 1) / E_BLK)  // 977
#define KW 1056                                  // W2T row length: 1024 + 32 (b2 fold)
#define HS_STRIDE 36                             // Hs2 row stride in dwords (16B aligned)

typedef unsigned short ushort;
typedef unsigned int uint;
typedef _Float16 half8v __attribute__((ext_vector_type(8)));
typedef _Float16 half2v __attribute__((ext_vector_type(2)));
typedef __attribute__((ext_vector_type(4))) float f32x4;

union UH8 { half8v h8; half2v h2[4]; ushort u[8]; uint q[4]; };
union UH2 { half2v h2; uint q; };

__device__ inline ushort f2h_bits(float f) {
    _Float16 h = (_Float16)f;
    return *reinterpret_cast<ushort*>(&h);
}

// ---------------- prep: zero agg(f16)/pool + W2T(f16) [32 l][1056 kk] ----------------
// kk < 1024:  W2T[l][kk] = W2.flat[kk*32 + l]
// kk >= 1024: W2T[l][1024+f] = b2[f*32 + l]    (b2 folded; paired with h == 1)
// GRID NOTE: must cover N_NODES*LATENT*2/16 = 200000 threads for the agg zeroing
// (R12 bug: 391 blocks left half of aggh poisoned -> 0xAAAA f16 = -0.0208 errors).
__global__ void prep_kernel(const float* __restrict__ W2, const float* __restrict__ b2,
                            ushort* __restrict__ W2T, uint4* __restrict__ aggz,
                            float* __restrict__ pool, float* __restrict__ pcnt) {
    int i = blockIdx.x * blockDim.x + threadIdx.x;
    if (i < (N_NODES * LATENT * 2) / 16) aggz[i] = make_uint4(0u, 0u, 0u, 0u);  // agg f16 zeros
    if (i < 32 * 1024) {
        int kk = i >> 5, l = i & 31;
        W2T[l * KW + kk] = f2h_bits(W2[i]);   // coalesced read
    }
    if (i < 1024) {
        int f = i >> 5, l = i & 31;
        W2T[l * KW + 1024 + f] = f2h_bits(b2[i]);
    }
    if (i < N_GRAPHS * LATENT) pool[i] = 0.f;
    if (i < N_GRAPHS) pcnt[i] = 0.f;
}

// ---------------- edge kernel: MSG[E x 32] = G[E x 1056] @ W2T^T  (f16 MFMA) ----------------
// G[e, k*32+f] = h[e,k] * x[src_e, f]  (k<32) ;  G[e, 1024+f] = x[src_e, f]
// MFMA 16x16x32: A row i = lane&15, k-slot = (lane>>4)*8+b;
//                D col j = lane&15, row i = (lane>>4)*4 + reg.
// 512 threads = 8 waves; each wave owns 2 16-row M-tiles (256 edges/block).
// Scatter: packed f16 atomics (global_atomic_pk_add_f16), 2 cols per lane-atomic.
__global__ __launch_bounds__(512) void edge_mfma_kernel(
    const float* __restrict__ x, const int* __restrict__ ei,
    const float* __restrict__ ea, const float* __restrict__ W1,
    const float* __restrict__ b1, const ushort* __restrict__ W2T,
    __half* __restrict__ aggh)
{
    __shared__ __attribute__((aligned(16))) uint Hs2[E_BLK * HS_STRIDE]; // {h,h} f16, 36KB
    __shared__ __attribute__((aligned(16))) ushort W2q[32 * 256];        // 16KB; row=j (512B), swz ^((j&7)<<4)

    const int t = threadIdx.x;
    const int e0 = blockIdx.x * E_BLK;
    const int wv = t >> 6, lane = t & 63;
    const int g = lane >> 4, j16 = lane & 15;

    // ---- H = relu(ea @ W1 + b1) via K-padded f16 MFMA (f>=16 lanes hold zeros)
    UH8 bw[2];
    #pragma unroll
    for (int nt = 0; nt < 2; ++nt) {
        #pragma unroll
        for (int b = 0; b < 8; ++b) {
            float w = (g < 2) ? W1[(8 * g + b) * LATENT + nt * 16 + j16] : 0.f;
            bw[nt].u[b] = f2h_bits(w);
        }
    }
    float b1v[2] = { b1[j16], b1[16 + j16] };

    #pragma unroll
    for (int mt = 0; mt < 2; ++mt) {
        int mtg = 2 * wv + mt;               // 0..15
        int rowA = mtg * 16 + j16;
        int e = e0 + rowA; if (e >= N_EDGES) e = N_EDGES - 1;
        UH8 ae;
        if (g < 2) {
            const float4* p = (const float4*)(ea + (size_t)e * F_EDGE + 8 * g);
            float4 va = p[0], vb = p[1];
            ae.u[0] = f2h_bits(va.x); ae.u[1] = f2h_bits(va.y);
            ae.u[2] = f2h_bits(va.z); ae.u[3] = f2h_bits(va.w);
            ae.u[4] = f2h_bits(vb.x); ae.u[5] = f2h_bits(vb.y);
            ae.u[6] = f2h_bits(vb.z); ae.u[7] = f2h_bits(vb.w);
        } else {
            ae.q[0] = 0; ae.q[1] = 0; ae.q[2] = 0; ae.q[3] = 0;
        }
        #pragma unroll
        for (int nt = 0; nt < 2; ++nt) {
            f32x4 hacc = (f32x4){0.f, 0.f, 0.f, 0.f};
            hacc = __builtin_amdgcn_mfma_f32_16x16x32_f16(ae.h8, bw[nt].h8, hacc, 0, 0, 0);
            #pragma unroll
            for (int v = 0; v < 4; ++v) {
                int rowD = mtg * 16 + 4 * g + v;
                int col = nt * 16 + j16;
                float hval = fmaxf(hacc[v] + b1v[nt], 0.f);
                uint hb = (uint)f2h_bits(hval);
                Hs2[rowD * HS_STRIDE + col] = hb * 0x10001u;  // packed {h,h}
            }
        }
    }
    // b2-extension row: h == 1.0 for every edge (k = 32)
    if (t < E_BLK) Hs2[t * HS_STRIDE + 32] = 0x3C003C00u;

    // ---- x fragments read DIRECTLY as f32, converted once (f = 8g+b) per M-tile
    f32x4 acc[2][2];
    #pragma unroll
    for (int a = 0; a < 2; ++a)
        #pragma unroll
        for (int b = 0; b < 2; ++b) acc[a][b] = (f32x4){0.f, 0.f, 0.f, 0.f};

    UH8 xf[2];
    int myrow[2];
    #pragma unroll
    for (int mt = 0; mt < 2; ++mt) {
        int row = (2 * wv + mt) * 16 + j16;
        myrow[mt] = row;
        int e = e0 + row; if (e >= N_EDGES) e = N_EDGES - 1;
        int src = ei[e];
        const float4* p = (const float4*)(x + (size_t)src * F_IN + 8 * g);
        float4 va = p[0], vb = p[1];
        xf[mt].u[0] = f2h_bits(va.x); xf[mt].u[1] = f2h_bits(va.y);
        xf[mt].u[2] = f2h_bits(va.z); xf[mt].u[3] = f2h_bits(va.w);
        xf[mt].u[4] = f2h_bits(vb.x); xf[mt].u[5] = f2h_bits(vb.y);
        xf[mt].u[6] = f2h_bits(vb.z); xf[mt].u[7] = f2h_bits(vb.w);
    }

    // ---- b2-extension K-step: A = x fragment directly (h == 1)
    {
        UH8 bx0, bx1;
        *(uint4*)bx0.q = *(const uint4*)(W2T + (size_t)j16 * KW + 1024 + 8 * g);
        *(uint4*)bx1.q = *(const uint4*)(W2T + (size_t)(16 + j16) * KW + 1024 + 8 * g);
        #pragma unroll
        for (int mt = 0; mt < 2; ++mt) {
            acc[mt][0] = __builtin_amdgcn_mfma_f32_16x16x32_f16(xf[mt].h8, bx0.h8, acc[mt][0], 0, 0, 0);
            acc[mt][1] = __builtin_amdgcn_mfma_f32_16x16x32_f16(xf[mt].h8, bx1.h8, acc[mt][1], 0, 0, 0);
        }
    }

    __syncthreads();  // Hs2 (incl. cross-wave b2 row) visible to all

    // ---- K loop: 4 quarters of 256 kk, W2T staged per quarter (XOR-swizzled)
    for (int q = 0; q < 4; ++q) {
        if (q) __syncthreads();
        #pragma unroll
        for (int c = 0; c < 2; ++c) {
            int ch = c * 512 + t;           // 1024 uint4 = 16KB staged by 512 threads
            int lbyte = ch * 16;
            int jrow = lbyte >> 9;
            int off = lbyte & 511;
            uint4 val = *(const uint4*)((const char*)W2T + (size_t)jrow * (KW * 2) + q * 512 + off);
            *(uint4*)((char*)W2q + jrow * 512 + (off ^ ((jrow & 7) << 4))) = val;
        }
        __syncthreads();

        // batched h2 fetch: 8 packed {h,h} per M-tile for k = q*8 .. q*8+7
        uint hb[2][8];
        #pragma unroll
        for (int mt = 0; mt < 2; ++mt) {
            const uint* hp = Hs2 + myrow[mt] * HS_STRIDE + q * 8;
            uint4 a = *(const uint4*)hp;
            uint4 b = *(const uint4*)(hp + 4);
            hb[mt][0] = a.x; hb[mt][1] = a.y; hb[mt][2] = a.z; hb[mt][3] = a.w;
            hb[mt][4] = b.x; hb[mt][5] = b.y; hb[mt][6] = b.z; hb[mt][7] = b.w;
        }

        #pragma unroll
        for (int kst = 0; kst < 8; ++kst) {
            int kb = kst * 64 + g * 16;
            UH8 bf0, bf1;
            *(uint4*)bf0.q = *(const uint4*)((const char*)W2q + j16 * 512 + (kb ^ ((j16 & 7) << 4)));
            *(uint4*)bf1.q = *(const uint4*)((const char*)W2q + (16 + j16) * 512 + (kb ^ ((j16 & 7) << 4)));
            #pragma unroll
            for (int mt = 0; mt < 2; ++mt) {
                UH2 h2; h2.q = hb[mt][kst];
                UH8 af;
                #pragma unroll
                for (int p = 0; p < 4; ++p) af.h2[p] = h2.h2 * xf[mt].h2[p];  // v_pk_mul_f16
                acc[mt][0] = __builtin_amdgcn_mfma_f32_16x16x32_f16(af.h8, bf0.h8, acc[mt][0], 0, 0, 0);
                acc[mt][1] = __builtin_amdgcn_mfma_f32_16x16x32_f16(af.h8, bf1.h8, acc[mt][1], 0, 0, 0);
            }
        }
    }

    // ---- scatter-add to aggh[dst] with packed-f16 atomics (2 cols per lane-atomic)
    const int odd = j16 & 1;
    #pragma unroll
    for (int mt = 0; mt < 2; ++mt) {
        int rowb = (2 * wv + mt) * 16 + 4 * g;
        #pragma unroll
        for (int v = 0; v < 4; ++v) {
            int e = e0 + rowb + v;
            float a0 = acc[mt][0][v], a1 = acc[mt][1][v];
            float p0 = __shfl_xor(a0, 1);
            float p1 = __shfl_xor(a1, 1);
            if (e < N_EDGES) {
                int dst = ei[N_EDGES + e];
                __half2 hv = odd ? __floats2half2_rn(p1, a1) : __floats2half2_rn(a0, p0);
                int col = odd ? (15 + j16) : j16;
                unsafeAtomicAdd((__half2*)(aggh + (size_t)dst * LATENT + col), hv);
            }
        }
    }
}

// ---------------- node update + global mean pool ----------------
// Lane l owns column l; each 32-lane group walks VN consecutive nodes with a running
// per-graph partial sum (batch sorted -> ~1 atomic flush per graph-run per stripe).
#define VN 8
__global__ __launch_bounds__(256) void nodepool_kernel(
    const float* __restrict__ x, const __half* __restrict__ aggh,
    const float* __restrict__ root, const float* __restrict__ cbias,
    const int* __restrict__ batch, float* __restrict__ pool,
    float* __restrict__ pcnt)
{
    int t = threadIdx.x;
    int l = t & 31;
    int stripe = t >> 5;  // 0..7
    int v0 = (blockIdx.x * 8 + stripe) * VN;
    float rc[F_IN];
    #pragma unroll
    for (int f = 0; f < F_IN; ++f) rc[f] = root[f * LATENT + l];
    float cbl = cbias[l];

    float sum = 0.f, cnt = 0.f;
    int gcur = -1;
    for (int i = 0; i < VN; ++i) {
        int v = v0 + i;
        if (v >= N_NODES) break;
        int g = batch[v];
        if (g != gcur) {
            if (gcur >= 0) {
                atomicAdd(&pool[gcur * LATENT + l], sum);
                if (l == 0) atomicAdd(&pcnt[gcur], cnt);
            }
            gcur = g; sum = 0.f; cnt = 0.f;
        }
        float xv = x[(size_t)v * F_IN + l];     // coalesced
        float a = __half2float(aggh[(size_t)v * LATENT + l]) + cbl;
        #pragma unroll
        for (int f = 0; f < F_IN; ++f) {
            float xfv = __shfl(xv, (t & 32) | f);
            a += xfv * rc[f];
        }
        sum += fmaxf(a, 0.f);
        cnt += 1.f;
    }
    if (gcur >= 0) {
        atomicAdd(&pool[gcur * LATENT + l], sum);
        if (l == 0) atomicAdd(&pcnt[gcur], cnt);
    }
}

// ---------------- final FC ----------------
__global__ void final_kernel(const float* __restrict__ pool, const float* __restrict__ pcnt,
                             const float* __restrict__ fcw, const float* __restrict__ fcb,
                             float* __restrict__ out)
{
    int t = blockIdx.x * blockDim.x + threadIdx.x;
    int gr = t >> 7, j = t & 127;
    if (gr >= N_GRAPHS) return;
    float inv = 1.0f / fmaxf(pcnt[gr], 1.0f);
    float o = fcb[j];
    #pragma unroll 8
    for (int l = 0; l < LATENT; ++l) {
        float pv = fmaxf(pool[gr * LATENT + l] * inv, 0.0f);
        o += pv * fcw[l * EMBED + j];
    }
    out[gr * EMBED + j] = o;
}

extern "C" void kernel_launch(void* const* d_in, const int* in_sizes, int n_in,
                              void* d_out, int out_size, void* d_ws, size_t ws_size,
                              hipStream_t stream)
{
    const float* x     = (const float*)d_in[0];
    const int*   ei    = (const int*)d_in[1];
    const float* ea    = (const float*)d_in[2];
    const int*   batch = (const int*)d_in[3];
    const float* W1    = (const float*)d_in[4];
    const float* b1    = (const float*)d_in[5];
    const float* W2    = (const float*)d_in[6];
    const float* b2    = (const float*)d_in[7];
    const float* root  = (const float*)d_in[8];
    const float* cb    = (const float*)d_in[9];
    const float* fcw   = (const float*)d_in[10];
    const float* fcb   = (const float*)d_in[11];
    float* out = (float*)d_out;

    char* w = (char*)d_ws;
    auto alloc = [&](size_t bytes) {
        char* p = w;
        w += (bytes + 255) & ~size_t(255);
        return p;
    };
    ushort* W2T  = (ushort*)alloc((size_t)32 * KW * 2);
    __half* aggh = (__half*)alloc((size_t)N_NODES * LATENT * 2);
    float*  pool = (float*)alloc(N_GRAPHS * LATENT * 4);
    float*  pcnt = (float*)alloc(N_GRAPHS * 4);

    // 782 blocks x 256 = 200192 threads >= 200000 needed for agg zeroing (R12 bugfix)
    prep_kernel<<<782, 256, 0, stream>>>(W2, b2, W2T, (uint4*)aggh, pool, pcnt);
    edge_mfma_kernel<<<N_EBLK, 512, 0, stream>>>(x, ei, ea, W1, b1, W2T, aggh);
    nodepool_kernel<<<(N_NODES + 8 * VN - 1) / (8 * VN), 256, 0, stream>>>(
        x, aggh, root, cb, batch, pool, pcnt);
    final_kernel<<<(N_GRAPHS * EMBED + 255) / 256, 256, 0, stream>>>(pool, pcnt, fcw, fcb, out);
}

// Round 14
// 62.951 us; speedup vs baseline: 1.2877x; 1.0010x over previous
//
#include <hip/hip_runtime.h>
#include <hip/hip_fp16.h>

#define N_NODES 50000
#define N_EDGES 250000
#define N_GRAPHS 512
#define F_IN 32
#define F_EDGE 16
#define LATENT 32
#define EMBED 128
#define E_BLK 256
#define N_EBLK ((N_EDGES + E_BLK - 1) / E_BLK)  // 977
#define KW 1056                                  // W2T row length: 1024 + 32 (b2 fold)
#define HS_STRIDE 36                             // Hs row stride in USHORTS (72B rows, 8B-aligned)

typedef unsigned short ushort;
typedef unsigned int uint;
typedef _Float16 half8v __attribute__((ext_vector_type(8)));
typedef _Float16 half2v __attribute__((ext_vector_type(2)));
typedef __attribute__((ext_vector_type(4))) float f32x4;

union UH8 { half8v h8; half2v h2[4]; ushort u[8]; uint q[4]; };
union UH2 { half2v h2; uint q; };

__device__ inline ushort f2h_bits(float f) {
    _Float16 h = (_Float16)f;
    return *reinterpret_cast<ushort*>(&h);
}

// ---------------- prep: zero agg(f16)/pool + W2T(f16) [32 l][1056 kk] ----------------
// kk < 1024:  W2T[l][kk] = W2.flat[kk*32 + l]
// kk >= 1024: W2T[l][1024+f] = b2[f*32 + l]    (b2 folded; paired with h == 1)
// GRID NOTE: must cover N_NODES*LATENT*2/16 = 200000 threads for the agg zeroing.
__global__ void prep_kernel(const float* __restrict__ W2, const float* __restrict__ b2,
                            ushort* __restrict__ W2T, uint4* __restrict__ aggz,
                            float* __restrict__ pool, float* __restrict__ pcnt) {
    int i = blockIdx.x * blockDim.x + threadIdx.x;
    if (i < (N_NODES * LATENT * 2) / 16) aggz[i] = make_uint4(0u, 0u, 0u, 0u);  // agg f16 zeros
    if (i < 32 * 1024) {
        int kk = i >> 5, l = i & 31;
        W2T[l * KW + kk] = f2h_bits(W2[i]);   // coalesced read
    }
    if (i < 1024) {
        int f = i >> 5, l = i & 31;
        W2T[l * KW + 1024 + f] = f2h_bits(b2[i]);
    }
    if (i < N_GRAPHS * LATENT) pool[i] = 0.f;
    if (i < N_GRAPHS) pcnt[i] = 0.f;
}

// ---------------- edge kernel: MSG[E x 32] = G[E x 1056] @ W2T^T  (f16 MFMA) ----------------
// G[e, k*32+f] = h[e,k] * x[src_e, f]  (k<32) ;  G[e, 1024+f] = x[src_e, f]
// MFMA 16x16x32: A row i = lane&15, k-slot = (lane>>4)*8+b;
//                D col j = lane&15, row i = (lane>>4)*4 + reg.
// 512 threads = 8 waves; each wave owns 2 16-row M-tiles (256 edges/block).
// Hs stored as raw ushort (18KB; repacked to {h,h} per quarter) -> LDS 34KB, 4 blocks/CU.
// Hs is intra-wave only (each wave reads back its own rows) -> no barrier needed for it.
// Scatter: packed f16 atomics (global_atomic_pk_add_f16), 2 cols per lane-atomic.
__global__ __launch_bounds__(512) void edge_mfma_kernel(
    const float* __restrict__ x, const int* __restrict__ ei,
    const float* __restrict__ ea, const float* __restrict__ W1,
    const float* __restrict__ b1, const ushort* __restrict__ W2T,
    __half* __restrict__ aggh)
{
    __shared__ __attribute__((aligned(16))) ushort Hs[E_BLK * HS_STRIDE]; // h f16, 18KB
    __shared__ __attribute__((aligned(16))) ushort W2q[32 * 256];         // 16KB; row=j (512B), swz ^((j&7)<<4)

    const int t = threadIdx.x;
    const int e0 = blockIdx.x * E_BLK;
    const int wv = t >> 6, lane = t & 63;
    const int g = lane >> 4, j16 = lane & 15;

    // ---- H = relu(ea @ W1 + b1) via K-padded f16 MFMA (f>=16 lanes hold zeros)
    UH8 bw[2];
    #pragma unroll
    for (int nt = 0; nt < 2; ++nt) {
        #pragma unroll
        for (int b = 0; b < 8; ++b) {
            float w = (g < 2) ? W1[(8 * g + b) * LATENT + nt * 16 + j16] : 0.f;
            bw[nt].u[b] = f2h_bits(w);
        }
    }
    float b1v[2] = { b1[j16], b1[16 + j16] };

    #pragma unroll
    for (int mt = 0; mt < 2; ++mt) {
        int mtg = 2 * wv + mt;               // 0..15
        int rowA = mtg * 16 + j16;
        int e = e0 + rowA; if (e >= N_EDGES) e = N_EDGES - 1;
        UH8 ae;
        if (g < 2) {
            const float4* p = (const float4*)(ea + (size_t)e * F_EDGE + 8 * g);
            float4 va = p[0], vb = p[1];
            ae.u[0] = f2h_bits(va.x); ae.u[1] = f2h_bits(va.y);
            ae.u[2] = f2h_bits(va.z); ae.u[3] = f2h_bits(va.w);
            ae.u[4] = f2h_bits(vb.x); ae.u[5] = f2h_bits(vb.y);
            ae.u[6] = f2h_bits(vb.z); ae.u[7] = f2h_bits(vb.w);
        } else {
            ae.q[0] = 0; ae.q[1] = 0; ae.q[2] = 0; ae.q[3] = 0;
        }
        #pragma unroll
        for (int nt = 0; nt < 2; ++nt) {
            f32x4 hacc = (f32x4){0.f, 0.f, 0.f, 0.f};
            hacc = __builtin_amdgcn_mfma_f32_16x16x32_f16(ae.h8, bw[nt].h8, hacc, 0, 0, 0);
            #pragma unroll
            for (int v = 0; v < 4; ++v) {
                int rowD = mtg * 16 + 4 * g + v;
                int col = nt * 16 + j16;
                float hval = fmaxf(hacc[v] + b1v[nt], 0.f);
                Hs[rowD * HS_STRIDE + col] = f2h_bits(hval);   // intra-wave rows only
            }
        }
    }
    // (no b2 row in Hs: cols 0-31 only are read; b2 handled by explicit bx MFMA below)

    // ---- x fragments read DIRECTLY as f32, converted once (f = 8g+b) per M-tile
    f32x4 acc[2][2];
    #pragma unroll
    for (int a = 0; a < 2; ++a)
        #pragma unroll
        for (int b = 0; b < 2; ++b) acc[a][b] = (f32x4){0.f, 0.f, 0.f, 0.f};

    UH8 xf[2];
    int myrow[2];
    #pragma unroll
    for (int mt = 0; mt < 2; ++mt) {
        int row = (2 * wv + mt) * 16 + j16;
        myrow[mt] = row;
        int e = e0 + row; if (e >= N_EDGES) e = N_EDGES - 1;
        int src = ei[e];
        const float4* p = (const float4*)(x + (size_t)src * F_IN + 8 * g);
        float4 va = p[0], vb = p[1];
        xf[mt].u[0] = f2h_bits(va.x); xf[mt].u[1] = f2h_bits(va.y);
        xf[mt].u[2] = f2h_bits(va.z); xf[mt].u[3] = f2h_bits(va.w);
        xf[mt].u[4] = f2h_bits(vb.x); xf[mt].u[5] = f2h_bits(vb.y);
        xf[mt].u[6] = f2h_bits(vb.z); xf[mt].u[7] = f2h_bits(vb.w);
    }

    // ---- b2-extension K-step: A = x fragment directly (h == 1)
    {
        UH8 bx0, bx1;
        *(uint4*)bx0.q = *(const uint4*)(W2T + (size_t)j16 * KW + 1024 + 8 * g);
        *(uint4*)bx1.q = *(const uint4*)(W2T + (size_t)(16 + j16) * KW + 1024 + 8 * g);
        #pragma unroll
        for (int mt = 0; mt < 2; ++mt) {
            acc[mt][0] = __builtin_amdgcn_mfma_f32_16x16x32_f16(xf[mt].h8, bx0.h8, acc[mt][0], 0, 0, 0);
            acc[mt][1] = __builtin_amdgcn_mfma_f32_16x16x32_f16(xf[mt].h8, bx1.h8, acc[mt][1], 0, 0, 0);
        }
    }

    // ---- K loop: 4 quarters of 256 kk, W2T staged per quarter (XOR-swizzled)
    for (int q = 0; q < 4; ++q) {
        if (q) __syncthreads();             // all waves done reading W2q(q-1)
        #pragma unroll
        for (int c = 0; c < 2; ++c) {
            int ch = c * 512 + t;           // 1024 uint4 = 16KB staged by 512 threads
            int lbyte = ch * 16;
            int jrow = lbyte >> 9;
            int off = lbyte & 511;
            uint4 val = *(const uint4*)((const char*)W2T + (size_t)jrow * (KW * 2) + q * 512 + off);
            *(uint4*)((char*)W2q + jrow * 512 + (off ^ ((jrow & 7) << 4))) = val;
        }
        __syncthreads();                    // W2q(q) visible

        // fetch this quarter's 8 h-values per M-tile (raw ushort) and repack to {h,h}
        uint hbp[2][8];
        #pragma unroll
        for (int mt = 0; mt < 2; ++mt) {
            const ushort* hp = Hs + myrow[mt] * HS_STRIDE + q * 8;
            uint2 ra = *(const uint2*)hp;        // cols q*8+0..3
            uint2 rb = *(const uint2*)(hp + 4);  // cols q*8+4..7
            uint raw[4] = { ra.x, ra.y, rb.x, rb.y };
            #pragma unroll
            for (int i = 0; i < 4; ++i) {
                uint u = raw[i];
                hbp[mt][2 * i]     = (u & 0xFFFFu) * 0x10001u;   // {h,h} of even col
                hbp[mt][2 * i + 1] = (u >> 16) * 0x10001u;       // {h,h} of odd col
            }
        }

        #pragma unroll
        for (int kst = 0; kst < 8; ++kst) {
            int kb = kst * 64 + g * 16;
            UH8 bf0, bf1;
            *(uint4*)bf0.q = *(const uint4*)((const char*)W2q + j16 * 512 + (kb ^ ((j16 & 7) << 4)));
            *(uint4*)bf1.q = *(const uint4*)((const char*)W2q + (16 + j16) * 512 + (kb ^ ((j16 & 7) << 4)));
            #pragma unroll
            for (int mt = 0; mt < 2; ++mt) {
                UH2 h2; h2.q = hbp[mt][kst];
                UH8 af;
                #pragma unroll
                for (int p = 0; p < 4; ++p) af.h2[p] = h2.h2 * xf[mt].h2[p];  // v_pk_mul_f16
                acc[mt][0] = __builtin_amdgcn_mfma_f32_16x16x32_f16(af.h8, bf0.h8, acc[mt][0], 0, 0, 0);
                acc[mt][1] = __builtin_amdgcn_mfma_f32_16x16x32_f16(af.h8, bf1.h8, acc[mt][1], 0, 0, 0);
            }
        }
    }

    // ---- scatter-add to aggh[dst] with packed-f16 atomics (2 cols per lane-atomic)
    const int odd = j16 & 1;
    #pragma unroll
    for (int mt = 0; mt < 2; ++mt) {
        int rowb = (2 * wv + mt) * 16 + 4 * g;
        #pragma unroll
        for (int v = 0; v < 4; ++v) {
            int e = e0 + rowb + v;
            float a0 = acc[mt][0][v], a1 = acc[mt][1][v];
            float p0 = __shfl_xor(a0, 1);
            float p1 = __shfl_xor(a1, 1);
            if (e < N_EDGES) {
                int dst = ei[N_EDGES + e];
                __half2 hv = odd ? __floats2half2_rn(p1, a1) : __floats2half2_rn(a0, p0);
                int col = odd ? (15 + j16) : j16;
                unsafeAtomicAdd((__half2*)(aggh + (size_t)dst * LATENT + col), hv);
            }
        }
    }
}

// ---------------- node update + global mean pool ----------------
// Lane l owns column l; each 32-lane group walks VN consecutive nodes with a running
// per-graph partial sum (batch sorted -> ~1 atomic flush per graph-run per stripe).
#define VN 8
__global__ __launch_bounds__(256) void nodepool_kernel(
    const float* __restrict__ x, const __half* __restrict__ aggh,
    const float* __restrict__ root, const float* __restrict__ cbias,
    const int* __restrict__ batch, float* __restrict__ pool,
    float* __restrict__ pcnt)
{
    int t = threadIdx.x;
    int l = t & 31;
    int stripe = t >> 5;  // 0..7
    int v0 = (blockIdx.x * 8 + stripe) * VN;
    float rc[F_IN];
    #pragma unroll
    for (int f = 0; f < F_IN; ++f) rc[f] = root[f * LATENT + l];
    float cbl = cbias[l];

    float sum = 0.f, cnt = 0.f;
    int gcur = -1;
    for (int i = 0; i < VN; ++i) {
        int v = v0 + i;
        if (v >= N_NODES) break;
        int g = batch[v];
        if (g != gcur) {
            if (gcur >= 0) {
                atomicAdd(&pool[gcur * LATENT + l], sum);
                if (l == 0) atomicAdd(&pcnt[gcur], cnt);
            }
            gcur = g; sum = 0.f; cnt = 0.f;
        }
        float xv = x[(size_t)v * F_IN + l];     // coalesced
        float a = __half2float(aggh[(size_t)v * LATENT + l]) + cbl;
        #pragma unroll
        for (int f = 0; f < F_IN; ++f) {
            float xfv = __shfl(xv, (t & 32) | f);
            a += xfv * rc[f];
        }
        sum += fmaxf(a, 0.f);
        cnt += 1.f;
    }
    if (gcur >= 0) {
        atomicAdd(&pool[gcur * LATENT + l], sum);
        if (l == 0) atomicAdd(&pcnt[gcur], cnt);
    }
}

// ---------------- final FC ----------------
__global__ void final_kernel(const float* __restrict__ pool, const float* __restrict__ pcnt,
                             const float* __restrict__ fcw, const float* __restrict__ fcb,
                             float* __restrict__ out)
{
    int t = blockIdx.x * blockDim.x + threadIdx.x;
    int gr = t >> 7, j = t & 127;
    if (gr >= N_GRAPHS) return;
    float inv = 1.0f / fmaxf(pcnt[gr], 1.0f);
    float o = fcb[j];
    #pragma unroll 8
    for (int l = 0; l < LATENT; ++l) {
        float pv = fmaxf(pool[gr * LATENT + l] * inv, 0.0f);
        o += pv * fcw[l * EMBED + j];
    }
    out[gr * EMBED + j] = o;
}

extern "C" void kernel_launch(void* const* d_in, const int* in_sizes, int n_in,
                              void* d_out, int out_size, void* d_ws, size_t ws_size,
                              hipStream_t stream)
{
    const float* x     = (const float*)d_in[0];
    const int*   ei    = (const int*)d_in[1];
    const float* ea    = (const float*)d_in[2];
    const int*   batch = (const int*)d_in[3];
    const float* W1    = (const float*)d_in[4];
    const float* b1    = (const float*)d_in[5];
    const float* W2    = (const float*)d_in[6];
    const float* b2    = (const float*)d_in[7];
    const float* root  = (const float*)d_in[8];
    const float* cb    = (const float*)d_in[9];
    const float* fcw   = (const float*)d_in[10];
    const float* fcb   = (const float*)d_in[11];
    float* out = (float*)d_out;

    char* w = (char*)d_ws;
    auto alloc = [&](size_t bytes) {
        char* p = w;
        w += (bytes + 255) & ~size_t(255);
        return p;
    };
    ushort* W2T  = (ushort*)alloc((size_t)32 * KW * 2);
    __half* aggh = (__half*)alloc((size_t)N_NODES * LATENT * 2);
    float*  pool = (float*)alloc(N_GRAPHS * LATENT * 4);
    float*  pcnt = (float*)alloc(N_GRAPHS * 4);

    // 782 blocks x 256 = 200192 threads >= 200000 needed for agg zeroing
    prep_kernel<<<782, 256, 0, stream>>>(W2, b2, W2T, (uint4*)aggh, pool, pcnt);
    edge_mfma_kernel<<<N_EBLK, 512, 0, stream>>>(x, ei, ea, W1, b1, W2T, aggh);
    nodepool_kernel<<<(N_NODES + 8 * VN - 1) / (8 * VN), 256, 0, stream>>>(
        x, aggh, root, cb, batch, pool, pcnt);
    final_kernel<<<(N_GRAPHS * EMBED + 255) / 256, 256, 0, stream>>>(pool, pcnt, fcw, fcb, out);
}